// Round 20
// baseline (203.736 us; speedup 1.0000x reference)
//
#include <hip/hip_runtime.h>

#define SS 1024
#define GG 10
#define FF 5
#define BB 8
#define CC 3
#define KK (2 * FF + 1)

typedef float f32x2 __attribute__((ext_vector_type(2), aligned(4)));

// ---------------------------------------------------------------------------
// Kernel 1: smooth the (B,1,G,G) offset grids with an 11x11 gaussian
// (edge-padded), scale by max_offset, clip, store field [B][2][G][G] in ws.
// ---------------------------------------------------------------------------
__global__ __launch_bounds__(256) void rds_smooth_kernel(
    const float* __restrict__ ox, const float* __restrict__ oy,
    const float* __restrict__ w, const void* __restrict__ max_move_p,
    float* __restrict__ gs)
{
    int idx = blockIdx.x * 256 + threadIdx.x;
    if (idx >= BB * 2 * GG * GG) return;
    int j  = idx % GG;
    int i  = (idx / GG) % GG;
    int ch = (idx / (GG * GG)) % 2;
    int b  = idx / (2 * GG * GG);

    const float* o = (ch == 0 ? ox : oy) + b * GG * GG;

    // max_move: python scalar; hedge int32 vs float32 storage
    int mi = *(const int*)max_move_p;
    float mv = (mi >= -100000 && mi <= 100000) ? (float)mi : __int_as_float(mi);
    float max_offset = 2.0f * mv / (float)SS;

    float acc = 0.0f;
    for (int u = 0; u < KK; ++u) {
        int yy = min(max(i + u - FF, 0), GG - 1);
        for (int v = 0; v < KK; ++v) {
            int xx = min(max(j + v - FF, 0), GG - 1);
            acc += o[yy * GG + xx] * w[u * KK + v];
        }
    }
    acc *= max_offset;
    acc = fminf(fmaxf(acc, -max_offset), max_offset);
    gs[idx] = acc;
}

// ---------------------------------------------------------------------------
// Kernel 2: 256-col x 32-row tile per block (R15 restructure).
//
// R15 model (fits all 9 measured configs): MLP is NOT the limiter — three
// maximally different schedules tie (compiler 61.6 / pinned-G8 63.0 /
// LDS-DMA-G16 74.5 us). Wave lifetime 27k cy >> per-wave critical path
// (~3k at G=8) -> waves queue on the shared L1 miss path. Per-CU distinct
// miss-lines: 32 blocks x 3ch x ~8-row windows x ~360 cols ~ 1.1MB ~ 17k
// lines x ~300cy / ~32-deep miss queue ~ 160k cy ~ observed 151k. The old
// 4-row blocks re-missed each halo line on TWO different CUs and had zero
// L1 temporal reuse.
//
// Fix: 32 output rows per block (1024 blocks, 4/CU), channel-outer /
// row-inner loop. The gather window slides ~4 rows per row-group with
// 50-75% line overlap now hitting the SAME CU's L1; per-CU footprint drops
// ~1.7x. rowf setup amortized 8x; x-quantities hoisted. Loads are plain
// derefs (R12 proved the schedule style is irrelevant).
//
// Keeps: weight remap (d = x0-bclamp), row masks, nontemporal stores,
// identity block mapping (R9: XCD swizzle regressed, reverted).
// ---------------------------------------------------------------------------
__global__ __launch_bounds__(256, 2) void rds_deform_kernel(
    const float* __restrict__ x, const float* __restrict__ gs,
    float* __restrict__ out)
{
    int wg    = blockIdx.x;          // 1024 = b(8) x yt(32) x xseg(4)
    int xseg  = wg & 3;
    int yt    = (wg >> 2) & 31;
    int b     = wg >> 7;
    int tid   = threadIdx.x;
    int ybase = yt << 5;             // 32 rows per block
    int xc    = (xseg << 8) + tid;

    __shared__ float rowf[32][2][GG];   // 2560 floats = 10 KB

    const float GdS = (float)GG / (float)SS;

    // Fill 32 rows x 2 channels x 10 cols of y-interpolated field
    for (int k = tid; k < 32 * 2 * GG; k += 256) {
        int p  = k / (2 * GG);
        int r  = k - p * 2 * GG;
        int ch = r / GG;
        int j  = r - ch * GG;
        int y  = ybase + p;
        float sy  = fmaxf(((float)y + 0.5f) * GdS - 0.5f, 0.0f);
        int   i0y = min((int)sy, GG - 1);
        int   i1y = min(i0y + 1, GG - 1);
        float wyu = sy - (float)i0y;
        const float* gb = gs + (b * 2 + ch) * GG * GG;
        rowf[p][ch][j] = gb[i0y * GG + j] + wyu * (gb[i1y * GG + j] - gb[i0y * GG + j]);
    }
    __syncthreads();

    // ---- x-direction quantities: once per thread ----
    float sx  = fmaxf(((float)xc + 0.5f) * GdS - 0.5f, 0.0f);
    int   i0x = min((int)sx, GG - 1);
    int   i1x = min(i0x + 1, GG - 1);
    float wxu = sx - (float)i0x;
    float pxc = (float)xc * (2.0f / (float)(SS - 1)) - 1.0f;

    const float* xb = x + (size_t)b * CC * SS * SS;

    for (int c = 0; c < CC; ++c) {
        const float* img = xb + (size_t)c * SS * SS;
        float* op = out + ((size_t)(b * CC + c) * SS + ybase) * SS + xc;

        #pragma unroll 4
        for (int p = 0; p < 32; ++p) {
            float r0a = rowf[p][0][i0x], r0b = rowf[p][0][i1x];
            float r1a = rowf[p][1][i0x], r1b = rowf[p][1][i1x];
            float gxv = r0a + wxu * (r0b - r0a);
            float gyv = r1a + wxu * (r1b - r1a);

            float py  = (float)(ybase + p) * (2.0f / (float)(SS - 1)) - 1.0f;
            float gr0 = fminf(fmaxf(gxv + pxc, -1.0f), 1.0f);
            float gr1 = fminf(fmaxf(gyv + py,  -1.0f), 1.0f);

            // ((gr+1)*S-1)/2 == gr*512 + 511.5
            float ix = gr0 * 512.0f + 511.5f;
            float iy = gr1 * 512.0f + 511.5f;

            int   x0 = (int)floorf(ix);      // in [-1, SS-1] after clip
            int   y0 = (int)floorf(iy);
            int   y1 = y0 + 1;
            float wx = ix - (float)x0;
            float wy = iy - (float)y0;

            // pair at [bclamp, bclamp+1]; d in {-1,0,1} remaps weights
            int bclamp = min(max(x0, 0), SS - 2);
            int d      = x0 - bclamp;
            float wxa = (d == 0) ? (1.0f - wx) : ((d < 0) ? wx : 0.0f);
            float wxb = (d == 0) ? wx          : ((d < 0) ? 0.0f : (1.0f - wx));

            float my0 = ((unsigned)y0 < (unsigned)SS) ? 1.0f : 0.0f;
            float my1 = ((unsigned)y1 < (unsigned)SS) ? 1.0f : 0.0f;
            float wya = (1.0f - wy) * my0;
            float wyb = wy * my1;

            int cy0 = min(max(y0, 0), SS - 1);
            int cy1 = min(max(y1, 0), SS - 1);

            f32x2 A = *(const f32x2*)(img + cy0 * SS + bclamp);
            f32x2 B = *(const f32x2*)(img + cy1 * SS + bclamp);
            float v = wya * (A.x * wxa + A.y * wxb)
                    + wyb * (B.x * wxa + B.y * wxb);
            __builtin_nontemporal_store(v, op + (size_t)p * SS);
        }
    }
}

extern "C" void kernel_launch(void* const* d_in, const int* in_sizes, int n_in,
                              void* d_out, int out_size, void* d_ws, size_t ws_size,
                              hipStream_t stream) {
    const float* x        = (const float*)d_in[0];
    const float* offset_x = (const float*)d_in[1];
    const float* offset_y = (const float*)d_in[2];
    const float* weight   = (const float*)d_in[3];
    const void*  max_move = d_in[4];
    float* out = (float*)d_out;
    float* gs  = (float*)d_ws;   // [B][2][G][G] smoothed, scaled, clipped field

    int n1 = BB * 2 * GG * GG;   // 1600
    rds_smooth_kernel<<<(n1 + 255) / 256, 256, 0, stream>>>(
        offset_x, offset_y, weight, max_move, gs);

    int nblocks = BB * (SS / 32) * 4;   // 1024: (b, ytile32, xseg)
    rds_deform_kernel<<<nblocks, 256, 0, stream>>>(x, gs, out);
}